// Round 2
// baseline (337.462 us; speedup 1.0000x reference)
//
#include <hip/hip_runtime.h>
#include <stdint.h>

typedef float f32x4 __attribute__((ext_vector_type(4)));
typedef __bf16 bfrag __attribute__((ext_vector_type(8)));
typedef unsigned short us4 __attribute__((ext_vector_type(4)));

__device__ __forceinline__ unsigned short f2bf(float f) {
  unsigned u = __float_as_uint(f);
  u += 0x7fff + ((u >> 16) & 1);   // RNE
  return (unsigned short)(u >> 16);
}
__device__ __forceinline__ float bf2f(unsigned short s) {
  return __uint_as_float(((unsigned)s) << 16);
}

// ---------------- kernel 0: transpose+convert weights to bf16 ----------------
__global__ __launch_bounds__(256)
void conv_w_k(const float* __restrict__ Wg, const float* __restrict__ Wb,
              unsigned short* __restrict__ WgT, unsigned short* __restrict__ WbT) {
  int i = blockIdx.x * 256 + threadIdx.x;
  if (i < 512 * 256) { int k = i >> 8, c = i & 255; WgT[c * 512 + k] = f2bf(Wg[i]); }
  if (i < 256 * 256) { int k = i >> 8, c = i & 255; WbT[c * 256 + k] = f2bf(Wb[i]); }
}

// ---------------- fused: seq_fts GEMM + adj-mult + PReLU + mean --------------
// BM=64 (4 batches), BN=256, BK=64. 4 waves, wave tile 32x128 (acc[2][8]).
// LDS: smA 8KB | smB 32KB; sf (32x256 bf16 = 16KB) reuses [0,16KB) after loop.
__global__ __launch_bounds__(256, 3)
void fused1_k(const float* __restrict__ A, const unsigned short* __restrict__ Bt,
              const float* __restrict__ adj, const float* __restrict__ b_gcn,
              const float* __restrict__ prelu_a,
              float* __restrict__ Cout, float* __restrict__ Hmv) {
  __shared__ char sm[40960];
  char* const smA = sm;
  char* const smB = sm + 8192;
  unsigned short* const sf = (unsigned short*)sm;   // 32 rows x 256 cols bf16

  const int t = threadIdx.x;
  const int lane = t & 63;
  const int wid = t >> 6;
  const int wm = wid >> 1, wn = wid & 1;
  const int lrow = lane & 15, lgrp = lane >> 4;
  const int wg = blockIdx.x;
  const int K = 512;

  f32x4 acc[2][8];
#pragma unroll
  for (int m = 0; m < 2; m++)
#pragma unroll
    for (int n = 0; n < 8; n++) acc[m][n] = (f32x4)0.0f;

  for (int kc = 0; kc < 8; ++kc) {
    const int k0 = kc << 6;
    // --- load A: coalesced; chunk c=i*256+t -> row=c>>4, slot=c&15 ---
    f32x4 av[4];
#pragma unroll
    for (int i = 0; i < 4; i++) {
      int c = i * 256 + t;
      int row = c >> 4, slot = c & 15;
      av[i] = *(const f32x4*)(A + (size_t)(wg * 64 + row) * K + k0 + slot * 4);
    }
    // --- load B: 8 x 16B per thread (256B-contig segments per col) ---
    uint4 bv[8];
#pragma unroll
    for (int i = 0; i < 8; i++) {
      int idx = i * 256 + t;
      int col = idx >> 3, slot = t & 7;
      bv[i] = *(const uint4*)(Bt + (size_t)col * K + k0 + slot * 8);
    }
    __syncthreads();
    // --- write A (convert to bf16), 8B per chunk, 16B-slot XOR swizzle ---
#pragma unroll
    for (int i = 0; i < 4; i++) {
      int c = i * 256 + t;
      int row = c >> 4, slot = c & 15;
      us4 w;
      w.x = f2bf(av[i].x); w.y = f2bf(av[i].y);
      w.z = f2bf(av[i].z); w.w = f2bf(av[i].w);
      *(us4*)(smA + row * 128 + (((slot >> 1) ^ (row & 7)) << 4) + (slot & 1) * 8) = w;
    }
    // --- write B ---
#pragma unroll
    for (int i = 0; i < 8; i++) {
      int idx = i * 256 + t;
      int col = idx >> 3, slot = t & 7;
      *(uint4*)(smB + col * 128 + ((slot ^ (col & 7)) << 4)) = bv[i];
    }
    __syncthreads();
    // --- compute: 2 k-steps of 32 ---
#pragma unroll
    for (int kk = 0; kk < 2; kk++) {
      bfrag af[2], bfv[8];
#pragma unroll
      for (int m = 0; m < 2; m++) {
        int row = (wm * 2 + m) * 16 + lrow;
        int slot = kk * 4 + lgrp;
        af[m] = *(const bfrag*)(smA + row * 128 + ((slot ^ (row & 7)) << 4));
      }
#pragma unroll
      for (int n = 0; n < 8; n++) {
        int col = (wn * 8 + n) * 16 + lrow;
        int slot = kk * 4 + lgrp;
        bfv[n] = *(const bfrag*)(smB + col * 128 + ((slot ^ (col & 7)) << 4));
      }
#pragma unroll
      for (int m = 0; m < 2; m++)
#pragma unroll
        for (int n = 0; n < 8; n++)
          acc[m][n] = __builtin_amdgcn_mfma_f32_16x16x32_bf16(af[m], bfv[n], acc[m][n], 0, 0, 0);
    }
  }
  __syncthreads();   // staging LDS dead from here

  const float pa = prelu_a[0];
  const f32x4 bg = *(const f32x4*)(b_gcn + lane * 4);

  // Two half-phases: phase h covers rows [h*32, h*32+32) = local batches h*2,h*2+1
  for (int h = 0; h < 2; ++h) {
    if (wm == h) {
      // write this wave's acc quadrant into sf (C layout: row=lgrp*4+rr, col=lrow)
#pragma unroll
      for (int m = 0; m < 2; m++)
#pragma unroll
        for (int n = 0; n < 8; n++) {
          int col = (wn * 8 + n) * 16 + lrow;
#pragma unroll
          for (int rr = 0; rr < 4; rr++) {
            int lr2 = m * 16 + lgrp * 4 + rr;   // 0..31
            sf[lr2 * 256 + col] = f2bf(acc[m][n][rr]);
          }
        }
    }
    __syncthreads();
    if (wm == h) {
      const int b = wg * 4 + h * 2 + wn;   // wave wn handles one batch
      f32x4 sfr[16];
#pragma unroll
      for (int mm = 0; mm < 16; mm++) {
        us4 q = *(const us4*)(sf + (wn * 16 + mm) * 256 + lane * 4);
        f32x4 v;
        v.x = bf2f(q.x); v.y = bf2f(q.y); v.z = bf2f(q.z); v.w = bf2f(q.w);
        sfr[mm] = v;
      }
      const float* adjb = adj + (size_t)b * 256;
      f32x4 cacc = (f32x4)0.0f;
      f32x4 hmv = (f32x4)0.0f;
#pragma unroll
      for (int n = 0; n < 16; n++) {
        f32x4 a4 = (f32x4)0.0f;
#pragma unroll
        for (int m = 0; m < 16; m++) a4 += adjb[n * 16 + m] * sfr[m];
        a4 += bg;
        f32x4 hv;
        hv.x = a4.x >= 0.f ? a4.x : pa * a4.x;
        hv.y = a4.y >= 0.f ? a4.y : pa * a4.y;
        hv.z = a4.z >= 0.f ? a4.z : pa * a4.z;
        hv.w = a4.w >= 0.f ? a4.w : pa * a4.w;
        if (n < 15) cacc += hv; else hmv = hv;
      }
      cacc *= (1.0f / 15.0f);
      *(f32x4*)(Cout + (size_t)b * 256 + lane * 4) = cacc;
      *(f32x4*)(Hmv + (size_t)b * 256 + lane * 4) = hmv;
    }
    __syncthreads();
  }
}

// ---------------- gemm2: T[8192][256] = HMV (f32->bf16) @ WbT, K=256 ---------
__global__ __launch_bounds__(256, 3)
void gemm2_k(const float* __restrict__ A, const unsigned short* __restrict__ Bt,
             float* __restrict__ Out) {
  __shared__ char sm[40960];
  char* const smA = sm;
  char* const smB = sm + 8192;
  const int t = threadIdx.x;
  const int lane = t & 63;
  const int wid = t >> 6;
  const int wm = wid >> 1, wn = wid & 1;
  const int lrow = lane & 15, lgrp = lane >> 4;
  const int wg = blockIdx.x;
  const int K = 256;

  f32x4 acc[2][8];
#pragma unroll
  for (int m = 0; m < 2; m++)
#pragma unroll
    for (int n = 0; n < 8; n++) acc[m][n] = (f32x4)0.0f;

  for (int kc = 0; kc < 4; ++kc) {
    const int k0 = kc << 6;
    f32x4 av[4];
#pragma unroll
    for (int i = 0; i < 4; i++) {
      int c = i * 256 + t;
      int row = c >> 4, slot = c & 15;
      av[i] = *(const f32x4*)(A + (size_t)(wg * 64 + row) * K + k0 + slot * 4);
    }
    uint4 bv[8];
#pragma unroll
    for (int i = 0; i < 8; i++) {
      int idx = i * 256 + t;
      int col = idx >> 3, slot = t & 7;
      bv[i] = *(const uint4*)(Bt + (size_t)col * K + k0 + slot * 8);
    }
    __syncthreads();
#pragma unroll
    for (int i = 0; i < 4; i++) {
      int c = i * 256 + t;
      int row = c >> 4, slot = c & 15;
      us4 w;
      w.x = f2bf(av[i].x); w.y = f2bf(av[i].y);
      w.z = f2bf(av[i].z); w.w = f2bf(av[i].w);
      *(us4*)(smA + row * 128 + (((slot >> 1) ^ (row & 7)) << 4) + (slot & 1) * 8) = w;
    }
#pragma unroll
    for (int i = 0; i < 8; i++) {
      int idx = i * 256 + t;
      int col = idx >> 3, slot = t & 7;
      *(uint4*)(smB + col * 128 + ((slot ^ (col & 7)) << 4)) = bv[i];
    }
    __syncthreads();
#pragma unroll
    for (int kk = 0; kk < 2; kk++) {
      bfrag af[2], bfv[8];
#pragma unroll
      for (int m = 0; m < 2; m++) {
        int row = (wm * 2 + m) * 16 + lrow;
        int slot = kk * 4 + lgrp;
        af[m] = *(const bfrag*)(smA + row * 128 + ((slot ^ (row & 7)) << 4));
      }
#pragma unroll
      for (int n = 0; n < 8; n++) {
        int col = (wn * 8 + n) * 16 + lrow;
        int slot = kk * 4 + lgrp;
        bfv[n] = *(const bfrag*)(smB + col * 128 + ((slot ^ (col & 7)) << 4));
      }
#pragma unroll
      for (int m = 0; m < 2; m++)
#pragma unroll
        for (int n = 0; n < 8; n++)
          acc[m][n] = __builtin_amdgcn_mfma_f32_16x16x32_bf16(af[m], bfv[n], acc[m][n], 0, 0, 0);
    }
  }
#pragma unroll
  for (int m = 0; m < 2; m++) {
    int rbase = wg * 64 + (wm * 2 + m) * 16 + lgrp * 4;
#pragma unroll
    for (int n = 0; n < 8; n++) {
      int col = (wn * 8 + n) * 16 + lrow;
#pragma unroll
      for (int rr = 0; rr < 4; rr++)
        Out[(size_t)(rbase + rr) * 256 + col] = acc[m][n][rr];
    }
  }
}

// ---------------- epi2: bilinear scores, norms, loss -------------------------
__global__ __launch_bounds__(256)
void epi2_k(const float* __restrict__ T, const float* __restrict__ C,
            const float* __restrict__ Hmv, const float* __restrict__ b_bil,
            float* __restrict__ out) {
  const int lane = threadIdx.x & 63;
  const int b = blockIdx.x * 4 + (threadIdx.x >> 6);
  const int bp = (b == 0) ? 8190 : (b - 1);
  f32x4 tv = *(const f32x4*)(T + (size_t)b * 256 + lane * 4);
  f32x4 cv = *(const f32x4*)(C + (size_t)b * 256 + lane * 4);
  f32x4 cp = *(const f32x4*)(C + (size_t)bp * 256 + lane * 4);
  f32x4 hv = *(const f32x4*)(Hmv + (size_t)b * 256 + lane * 4);
  f32x4 d0 = hv - cv + 1e-6f;
  f32x4 d1 = hv - cp + 1e-6f;
  float s0 = tv.x * cv.x + tv.y * cv.y + tv.z * cv.z + tv.w * cv.w;
  float s1 = tv.x * cp.x + tv.y * cp.y + tv.z * cp.z + tv.w * cp.w;
  float p = d0.x * d0.x + d0.y * d0.y + d0.z * d0.z + d0.w * d0.w;
  float q = d1.x * d1.x + d1.y * d1.y + d1.z * d1.z + d1.w * d1.w;
#pragma unroll
  for (int m = 1; m < 64; m <<= 1) {
    s0 += __shfl_xor(s0, m, 64);
    s1 += __shfl_xor(s1, m, 64);
    p  += __shfl_xor(p, m, 64);
    q  += __shfl_xor(q, m, 64);
  }
  if (lane == 0) {
    float bb = b_bil[0];
    out[b] = s0 + bb;
    out[8192 + b] = s1 + bb;
    out[16384 + b] = fmaxf(0.0f, sqrtf(p) - sqrtf(q) + 0.5f);
  }
}

// ---------------- launch -----------------------------------------------------
extern "C" void kernel_launch(void* const* d_in, const int* in_sizes, int n_in,
                              void* d_out, int out_size, void* d_ws, size_t ws_size,
                              hipStream_t stream) {
  (void)in_sizes; (void)n_in; (void)out_size; (void)ws_size;
  const float* seq1 = (const float*)d_in[0];
  const float* adj  = (const float*)d_in[1];
  const float* Wg   = (const float*)d_in[2];
  const float* bg   = (const float*)d_in[3];
  const float* pa   = (const float*)d_in[4];
  const float* Wb   = (const float*)d_in[5];
  const float* bb   = (const float*)d_in[6];
  float* out = (float*)d_out;
  char* ws = (char*)d_ws;

  unsigned short* WgT = (unsigned short*)(ws);                 // 256 KB
  unsigned short* WbT = (unsigned short*)(ws + 262144);        // 128 KB
  float* C   = (float*)(ws + 524288);                          // 8 MB
  float* HMV = (float*)(ws + 524288 + 8388608);                // 8 MB
  float* T   = (float*)(ws + 524288 + 16777216);               // 8 MB

  hipLaunchKernelGGL(conv_w_k, dim3(512), dim3(256), 0, stream, Wg, Wb, WgT, WbT);
  hipLaunchKernelGGL(fused1_k, dim3(2048), dim3(256), 0, stream, seq1, WgT, adj, bg, pa, C, HMV);
  hipLaunchKernelGGL(gemm2_k, dim3(128), dim3(256), 0, stream, HMV, WbT, T);
  hipLaunchKernelGGL(epi2_k, dim3(2048), dim3(256), 0, stream, T, C, HMV, bb, out);
}

// Round 3
// 104.748 us; speedup vs baseline: 3.2216x; 3.2216x over previous
//
#include <hip/hip_runtime.h>
#include <stdint.h>

typedef float f32x4 __attribute__((ext_vector_type(4)));
typedef __bf16 bfrag __attribute__((ext_vector_type(8)));
typedef unsigned short us4 __attribute__((ext_vector_type(4)));

__device__ __forceinline__ unsigned short f2bf(float f) {
  unsigned u = __float_as_uint(f);
  u += 0x7fff + ((u >> 16) & 1);   // RNE
  return (unsigned short)(u >> 16);
}
__device__ __forceinline__ float bf2f(unsigned short s) {
  return __uint_as_float(((unsigned)s) << 16);
}

typedef __attribute__((address_space(3))) void lds_vp;
typedef __attribute__((address_space(1))) void gl_vp;
__device__ __forceinline__ void gload16(const void* g, void* l) {
  __builtin_amdgcn_global_load_lds((const gl_vp*)g, (lds_vp*)l, 16, 0, 0);
}

// ---------------- kernel 0: transpose+convert weights to bf16 ----------------
__global__ __launch_bounds__(256)
void conv_w_k(const float* __restrict__ Wg, const float* __restrict__ Wb,
              unsigned short* __restrict__ WgT, unsigned short* __restrict__ WbT) {
  int i = blockIdx.x * 256 + threadIdx.x;
  if (i < 512 * 256) { int k = i >> 8, c = i & 255; WgT[c * 512 + k] = f2bf(Wg[i]); }
  if (i < 256 * 256) { int k = i >> 8, c = i & 255; WbT[c * 256 + k] = f2bf(Wb[i]); }
}

// ---------------- staging: global -> LDS direct, pre-swizzled source ---------
// A tile: 128 rows x 32 f32 (16KB). 16B slot s in row-chunk; s' = s ^ swzA(row).
// B tile: 256 cols x 32 bf16 (16KB). 16B slot s; s' = s ^ ((col^(col>>2))&3).
template <int KF>
__device__ __forceinline__ void stage_tiles(const float* __restrict__ A,
                                            const unsigned short* __restrict__ Bt,
                                            char* buf, int wg, int kc, int t) {
#pragma unroll
  for (int i = 0; i < 2; i++) {
    int c = i * 512 + t;
    int row = c >> 3, s = c & 7;
    int sp = s ^ (((row & 3) << 1) | ((row >> 2) & 1));
    gload16(A + (size_t)(wg * 128 + row) * KF + kc * 32 + sp * 4, buf + c * 16);
  }
#pragma unroll
  for (int i = 0; i < 2; i++) {
    int c = i * 512 + t;
    int col = c >> 2, s = c & 3;
    int sp = s ^ ((col ^ (col >> 2)) & 3);
    gload16(Bt + (size_t)col * KF + kc * 32 + sp * 8, buf + 16384 + c * 16);
  }
}

// ---------------- big GEMM: Out[M][256] = A[M][KF](f32->bf16) @ BtT ----------
// BM=128, BN=256, BK=32. 512 threads, 8 waves (wm 0..1 x wn 0..3), wave tile
// 64x64, acc[4][4]. Double-buffered LDS 2x32KB; counted vmcnt pipeline.
// FUSED=1: adj epilogue (h1=adj@sf+b, PReLU, c=mean, h_mv) via LDS sf reuse.
template <int KF, int FUSED>
__global__ __launch_bounds__(512, 4)
void gemm_big(const float* __restrict__ A, const unsigned short* __restrict__ Bt,
              const float* __restrict__ adj, const float* __restrict__ b_gcn,
              const float* __restrict__ prelu_a,
              float* __restrict__ O1, float* __restrict__ O2) {
  __shared__ char sm[65536];
  const int t = threadIdx.x;
  const int lane = t & 63;
  const int wid = t >> 6;
  const int wm = wid >> 2, wn = wid & 3;
  const int lrow = lane & 15, lgrp = lane >> 4;
  const int wg = blockIdx.x;
  constexpr int NCH = KF / 32;

  f32x4 acc[4][4];
#pragma unroll
  for (int m = 0; m < 4; m++)
#pragma unroll
    for (int n = 0; n < 4; n++) acc[m][n] = (f32x4)0.0f;

  stage_tiles<KF>(A, Bt, sm, wg, 0, t);

  for (int kc = 0; kc < NCH; ++kc) {
    char* cur = sm + (kc & 1) * 32768;
    if (kc + 1 < NCH) {
      stage_tiles<KF>(A, Bt, sm + ((kc + 1) & 1) * 32768, wg, kc + 1, t);
      asm volatile("s_waitcnt vmcnt(4)" ::: "memory");
    } else {
      asm volatile("s_waitcnt vmcnt(0)" ::: "memory");
    }
    __builtin_amdgcn_s_barrier();
    asm volatile("" ::: "memory");

    bfrag bf[4];
#pragma unroll
    for (int n = 0; n < 4; n++) {
      int bcol = wn * 64 + n * 16 + lrow;
      int sB = (bcol ^ (bcol >> 2)) & 3;
      bf[n] = *(const bfrag*)(cur + 16384 + bcol * 64 + ((lgrp ^ sB) << 4));
    }
#pragma unroll
    for (int m = 0; m < 4; m++) {
      int arow = wm * 64 + m * 16 + lrow;
      int sw = ((arow & 3) << 1) | ((arow >> 2) & 1);
      f32x4 lo = *(const f32x4*)(cur + arow * 128 + (((lgrp * 2) ^ sw) << 4));
      f32x4 hi = *(const f32x4*)(cur + arow * 128 + (((lgrp * 2 + 1) ^ sw) << 4));
      bfrag am;
      am[0] = (__bf16)lo.x; am[1] = (__bf16)lo.y; am[2] = (__bf16)lo.z; am[3] = (__bf16)lo.w;
      am[4] = (__bf16)hi.x; am[5] = (__bf16)hi.y; am[6] = (__bf16)hi.z; am[7] = (__bf16)hi.w;
#pragma unroll
      for (int n = 0; n < 4; n++)
        acc[m][n] = __builtin_amdgcn_mfma_f32_16x16x32_bf16(am, bf[n], acc[m][n], 0, 0, 0);
    }
    __builtin_amdgcn_s_barrier();
    asm volatile("" ::: "memory");
  }

  if constexpr (FUSED) {
    // --- write acc tile into sf (reuses ALL 64KB of staging LDS) ---
    unsigned short* sf = (unsigned short*)sm;   // [128][256] bf16
#pragma unroll
    for (int m = 0; m < 4; m++) {
      int row = wm * 64 + m * 16 + lgrp * 4;
#pragma unroll
      for (int n = 0; n < 4; n++) {
        int col = wn * 64 + n * 16 + lrow;
#pragma unroll
        for (int rr = 0; rr < 4; rr++)
          sf[(row + rr) * 256 + col] = f2bf(acc[m][n][rr]);
      }
    }
    __builtin_amdgcn_s_barrier();
    asm volatile("" ::: "memory");

    // --- wave wid handles batch wg*8+wid: h1 = adj@sf + bg, PReLU, c, h_mv ---
    const float pa = prelu_a[0];
    const f32x4 bg = *(const f32x4*)(b_gcn + lane * 4);
    f32x4 sfr[16];
#pragma unroll
    for (int mm = 0; mm < 16; mm++) {
      us4 q = *(const us4*)(sf + (wid * 16 + mm) * 256 + lane * 4);
      f32x4 v;
      v.x = bf2f(q.x); v.y = bf2f(q.y); v.z = bf2f(q.z); v.w = bf2f(q.w);
      sfr[mm] = v;
    }
    const int b = wg * 8 + wid;
    const float* adjb = adj + (size_t)b * 256;
    f32x4 cacc = (f32x4)0.0f;
    f32x4 hmv = (f32x4)0.0f;
#pragma unroll
    for (int n = 0; n < 16; n++) {
      f32x4 a4 = (f32x4)0.0f;
#pragma unroll
      for (int m = 0; m < 16; m++) a4 += adjb[n * 16 + m] * sfr[m];
      a4 += bg;
      f32x4 hv;
      hv.x = a4.x >= 0.f ? a4.x : pa * a4.x;
      hv.y = a4.y >= 0.f ? a4.y : pa * a4.y;
      hv.z = a4.z >= 0.f ? a4.z : pa * a4.z;
      hv.w = a4.w >= 0.f ? a4.w : pa * a4.w;
      if (n < 15) cacc += hv; else hmv = hv;
    }
    cacc *= (1.0f / 15.0f);
    *(f32x4*)(O1 + (size_t)b * 256 + lane * 4) = cacc;
    *(f32x4*)(O2 + (size_t)b * 256 + lane * 4) = hmv;
  } else {
#pragma unroll
    for (int m = 0; m < 4; m++) {
      int rbase = wg * 128 + wm * 64 + m * 16 + lgrp * 4;
#pragma unroll
      for (int n = 0; n < 4; n++) {
        int col = wn * 64 + n * 16 + lrow;
#pragma unroll
        for (int rr = 0; rr < 4; rr++)
          O1[(size_t)(rbase + rr) * 256 + col] = acc[m][n][rr];
      }
    }
  }
}

// ---------------- epi2: bilinear scores, norms, loss -------------------------
__global__ __launch_bounds__(256)
void epi2_k(const float* __restrict__ T, const float* __restrict__ C,
            const float* __restrict__ Hmv, const float* __restrict__ b_bil,
            float* __restrict__ out) {
  const int lane = threadIdx.x & 63;
  const int b = blockIdx.x * 4 + (threadIdx.x >> 6);
  const int bp = (b == 0) ? 8190 : (b - 1);
  f32x4 tv = *(const f32x4*)(T + (size_t)b * 256 + lane * 4);
  f32x4 cv = *(const f32x4*)(C + (size_t)b * 256 + lane * 4);
  f32x4 cp = *(const f32x4*)(C + (size_t)bp * 256 + lane * 4);
  f32x4 hv = *(const f32x4*)(Hmv + (size_t)b * 256 + lane * 4);
  f32x4 d0 = hv - cv + 1e-6f;
  f32x4 d1 = hv - cp + 1e-6f;
  float s0 = tv.x * cv.x + tv.y * cv.y + tv.z * cv.z + tv.w * cv.w;
  float s1 = tv.x * cp.x + tv.y * cp.y + tv.z * cp.z + tv.w * cp.w;
  float p = d0.x * d0.x + d0.y * d0.y + d0.z * d0.z + d0.w * d0.w;
  float q = d1.x * d1.x + d1.y * d1.y + d1.z * d1.z + d1.w * d1.w;
#pragma unroll
  for (int m = 1; m < 64; m <<= 1) {
    s0 += __shfl_xor(s0, m, 64);
    s1 += __shfl_xor(s1, m, 64);
    p  += __shfl_xor(p, m, 64);
    q  += __shfl_xor(q, m, 64);
  }
  if (lane == 0) {
    float bb = b_bil[0];
    out[b] = s0 + bb;
    out[8192 + b] = s1 + bb;
    out[16384 + b] = fmaxf(0.0f, sqrtf(p) - sqrtf(q) + 0.5f);
  }
}

// ---------------- launch -----------------------------------------------------
extern "C" void kernel_launch(void* const* d_in, const int* in_sizes, int n_in,
                              void* d_out, int out_size, void* d_ws, size_t ws_size,
                              hipStream_t stream) {
  (void)in_sizes; (void)n_in; (void)out_size; (void)ws_size;
  const float* seq1 = (const float*)d_in[0];
  const float* adj  = (const float*)d_in[1];
  const float* Wg   = (const float*)d_in[2];
  const float* bg   = (const float*)d_in[3];
  const float* pa   = (const float*)d_in[4];
  const float* Wb   = (const float*)d_in[5];
  const float* bb   = (const float*)d_in[6];
  float* out = (float*)d_out;
  char* ws = (char*)d_ws;

  unsigned short* WgT = (unsigned short*)(ws);                 // 256 KB
  unsigned short* WbT = (unsigned short*)(ws + 262144);        // 128 KB
  float* C   = (float*)(ws + 524288);                          // 8 MB
  float* HMV = (float*)(ws + 524288 + 8388608);                // 8 MB
  float* T   = (float*)(ws + 524288 + 16777216);               // 8 MB

  hipLaunchKernelGGL(conv_w_k, dim3(512), dim3(256), 0, stream, Wg, Wb, WgT, WbT);
  hipLaunchKernelGGL((gemm_big<512, 1>), dim3(1024), dim3(512), 0, stream,
                     seq1, WgT, adj, bg, pa, C, HMV);
  hipLaunchKernelGGL((gemm_big<256, 0>), dim3(64), dim3(512), 0, stream,
                     HMV, WbT, nullptr, nullptr, nullptr, T, nullptr);
  hipLaunchKernelGGL(epi2_k, dim3(2048), dim3(256), 0, stream, T, C, HMV, bb, out);
}

// Round 4
// 100.301 us; speedup vs baseline: 3.3645x; 1.0443x over previous
//
#include <hip/hip_runtime.h>
#include <stdint.h>

typedef float f32x4 __attribute__((ext_vector_type(4)));
typedef __bf16 bfrag __attribute__((ext_vector_type(8)));
typedef unsigned short us4 __attribute__((ext_vector_type(4)));

__device__ __forceinline__ unsigned short f2bf(float f) {
  unsigned u = __float_as_uint(f);
  u += 0x7fff + ((u >> 16) & 1);   // RNE
  return (unsigned short)(u >> 16);
}
__device__ __forceinline__ float bf2f(unsigned short s) {
  return __uint_as_float(((unsigned)s) << 16);
}

typedef __attribute__((address_space(3))) void lds_vp;
typedef __attribute__((address_space(1))) void gl_vp;
__device__ __forceinline__ void gload16(const void* g, void* l) {
  __builtin_amdgcn_global_load_lds((const gl_vp*)g, (lds_vp*)l, 16, 0, 0);
}

// ---------------- kernel 0: transpose+convert weights to bf16 ----------------
__global__ __launch_bounds__(256)
void conv_w_k(const float* __restrict__ Wg, const float* __restrict__ Wb,
              unsigned short* __restrict__ WgT, unsigned short* __restrict__ WbT) {
  int i = blockIdx.x * 256 + threadIdx.x;
  if (i < 512 * 256) { int k = i >> 8, c = i & 255; WgT[c * 512 + k] = f2bf(Wg[i]); }
  if (i < 256 * 256) { int k = i >> 8, c = i & 255; WbT[c * 256 + k] = f2bf(Wb[i]); }
}

// ---------------- fused1: seq_fts GEMM + adj-mult + PReLU + mean -------------
// BM=128 (8 batches), BN=256, BK=32. 8 waves, wave tile 64x64 (acc[4][4]).
// global_load_lds direct staging, double-buffered, counted vmcnt.
__device__ __forceinline__ void stage1(const float* __restrict__ A,
                                       const unsigned short* __restrict__ Bt,
                                       char* buf, int wg, int kc, int t) {
#pragma unroll
  for (int i = 0; i < 2; i++) {
    int c = i * 512 + t;
    int row = c >> 3, s = c & 7;
    int sp = s ^ (((row & 3) << 1) | ((row >> 2) & 1));
    gload16(A + (size_t)(wg * 128 + row) * 512 + kc * 32 + sp * 4, buf + c * 16);
  }
#pragma unroll
  for (int i = 0; i < 2; i++) {
    int c = i * 512 + t;
    int col = c >> 2, s = c & 3;
    int sp = s ^ ((col ^ (col >> 2)) & 3);
    gload16(Bt + (size_t)col * 512 + kc * 32 + sp * 8, buf + 16384 + c * 16);
  }
}

__global__ __launch_bounds__(512, 4)
void fused1_k(const float* __restrict__ A, const unsigned short* __restrict__ Bt,
              const float* __restrict__ adj, const float* __restrict__ b_gcn,
              const float* __restrict__ prelu_a,
              float* __restrict__ Cout, float* __restrict__ Hmv) {
  __shared__ char sm[65536];
  const int t = threadIdx.x;
  const int lane = t & 63;
  const int wid = t >> 6;
  const int wm = wid >> 2, wn = wid & 3;
  const int lrow = lane & 15, lgrp = lane >> 4;
  const int wg = blockIdx.x;

  f32x4 acc[4][4];
#pragma unroll
  for (int m = 0; m < 4; m++)
#pragma unroll
    for (int n = 0; n < 4; n++) acc[m][n] = (f32x4)0.0f;

  stage1(A, Bt, sm, wg, 0, t);

  for (int kc = 0; kc < 16; ++kc) {
    char* cur = sm + (kc & 1) * 32768;
    if (kc + 1 < 16) {
      stage1(A, Bt, sm + ((kc + 1) & 1) * 32768, wg, kc + 1, t);
      asm volatile("s_waitcnt vmcnt(4)" ::: "memory");
    } else {
      asm volatile("s_waitcnt vmcnt(0)" ::: "memory");
    }
    __builtin_amdgcn_s_barrier();
    asm volatile("" ::: "memory");

    bfrag bf[4];
#pragma unroll
    for (int n = 0; n < 4; n++) {
      int bcol = wn * 64 + n * 16 + lrow;
      int sB = (bcol ^ (bcol >> 2)) & 3;
      bf[n] = *(const bfrag*)(cur + 16384 + bcol * 64 + ((lgrp ^ sB) << 4));
    }
#pragma unroll
    for (int m = 0; m < 4; m++) {
      int arow = wm * 64 + m * 16 + lrow;
      int sw = ((arow & 3) << 1) | ((arow >> 2) & 1);
      f32x4 lo = *(const f32x4*)(cur + arow * 128 + (((lgrp * 2) ^ sw) << 4));
      f32x4 hi = *(const f32x4*)(cur + arow * 128 + (((lgrp * 2 + 1) ^ sw) << 4));
      bfrag am;
      am[0] = (__bf16)lo.x; am[1] = (__bf16)lo.y; am[2] = (__bf16)lo.z; am[3] = (__bf16)lo.w;
      am[4] = (__bf16)hi.x; am[5] = (__bf16)hi.y; am[6] = (__bf16)hi.z; am[7] = (__bf16)hi.w;
#pragma unroll
      for (int n = 0; n < 4; n++)
        acc[m][n] = __builtin_amdgcn_mfma_f32_16x16x32_bf16(am, bf[n], acc[m][n], 0, 0, 0);
    }
    __builtin_amdgcn_s_barrier();
    asm volatile("" ::: "memory");
  }

  // --- write acc tile into sf bf16 [128][256] (reuses all 64KB staging LDS) ---
  unsigned short* sf = (unsigned short*)sm;
#pragma unroll
  for (int m = 0; m < 4; m++) {
    int row = wm * 64 + m * 16 + lgrp * 4;
#pragma unroll
    for (int n = 0; n < 4; n++) {
      int col = wn * 64 + n * 16 + lrow;
#pragma unroll
      for (int rr = 0; rr < 4; rr++)
        sf[(row + rr) * 256 + col] = f2bf(acc[m][n][rr]);
    }
  }
  __builtin_amdgcn_s_barrier();
  asm volatile("" ::: "memory");

  // --- wave wid handles batch wg*8+wid ---
  const float pa = prelu_a[0];
  const f32x4 bg = *(const f32x4*)(b_gcn + lane * 4);
  f32x4 sfr[16];
#pragma unroll
  for (int mm = 0; mm < 16; mm++) {
    us4 q = *(const us4*)(sf + (wid * 16 + mm) * 256 + lane * 4);
    f32x4 v;
    v.x = bf2f(q.x); v.y = bf2f(q.y); v.z = bf2f(q.z); v.w = bf2f(q.w);
    sfr[mm] = v;
  }
  const int b = wg * 8 + wid;
  const float* adjb = adj + (size_t)b * 256;
  f32x4 cacc = (f32x4)0.0f;
  f32x4 hmv = (f32x4)0.0f;
#pragma unroll
  for (int n = 0; n < 16; n++) {
    f32x4 a4 = (f32x4)0.0f;
#pragma unroll
    for (int m = 0; m < 16; m++) a4 += adjb[n * 16 + m] * sfr[m];
    a4 += bg;
    f32x4 hv;
    hv.x = a4.x >= 0.f ? a4.x : pa * a4.x;
    hv.y = a4.y >= 0.f ? a4.y : pa * a4.y;
    hv.z = a4.z >= 0.f ? a4.z : pa * a4.z;
    hv.w = a4.w >= 0.f ? a4.w : pa * a4.w;
    if (n < 15) cacc += hv; else hmv = hv;
  }
  cacc *= (1.0f / 15.0f);
  *(f32x4*)(Cout + (size_t)b * 256 + lane * 4) = cacc;
  *(f32x4*)(Hmv + (size_t)b * 256 + lane * 4) = hmv;
}

// ---------------- fused2: T = HMV@WbT (K=256) + bilinear + norms + loss ------
// BM=64 batches, BN=256 (full rows), BK=32, grid 128. 8 waves, wave tile
// 32x64 (acc[2][4]). After K-loop: sf f32 [64][256] in LDS, per-wave epilogue.
__device__ __forceinline__ void stage2(const float* __restrict__ A,
                                       const unsigned short* __restrict__ Bt,
                                       char* buf, int wg, int kc, int t) {
  {
    int c = t;                       // 512 chunks of 16B = 64 rows x 32 f32
    int row = c >> 3, s = c & 7;
    int sp = s ^ (((row & 3) << 1) | ((row >> 2) & 1));
    gload16(A + (size_t)(wg * 64 + row) * 256 + kc * 32 + sp * 4, buf + c * 16);
  }
#pragma unroll
  for (int i = 0; i < 2; i++) {
    int c = i * 512 + t;
    int col = c >> 2, s = c & 3;
    int sp = s ^ ((col ^ (col >> 2)) & 3);
    gload16(Bt + (size_t)col * 256 + kc * 32 + sp * 8, buf + 8192 + c * 16);
  }
}

__global__ __launch_bounds__(512)
void fused2_k(const float* __restrict__ A, const unsigned short* __restrict__ Bt,
              const float* __restrict__ C, const float* __restrict__ Hmv,
              const float* __restrict__ b_bil, float* __restrict__ out) {
  __shared__ char sm[65536];   // staging: 2 x (8KB A + 16KB B) = 48KB; sf reuse 64KB
  const int t = threadIdx.x;
  const int lane = t & 63;
  const int wid = t >> 6;
  const int wm = wid >> 2, wn = wid & 3;
  const int lrow = lane & 15, lgrp = lane >> 4;
  const int wg = blockIdx.x;

  f32x4 acc[2][4];
#pragma unroll
  for (int m = 0; m < 2; m++)
#pragma unroll
    for (int n = 0; n < 4; n++) acc[m][n] = (f32x4)0.0f;

  stage2(A, Bt, sm, wg, 0, t);

  for (int kc = 0; kc < 8; ++kc) {
    char* cur = sm + (kc & 1) * 24576;
    if (kc + 1 < 8) {
      stage2(A, Bt, sm + ((kc + 1) & 1) * 24576, wg, kc + 1, t);
      asm volatile("s_waitcnt vmcnt(3)" ::: "memory");
    } else {
      asm volatile("s_waitcnt vmcnt(0)" ::: "memory");
    }
    __builtin_amdgcn_s_barrier();
    asm volatile("" ::: "memory");

    bfrag bf[4];
#pragma unroll
    for (int n = 0; n < 4; n++) {
      int bcol = wn * 64 + n * 16 + lrow;
      int sB = (bcol ^ (bcol >> 2)) & 3;
      bf[n] = *(const bfrag*)(cur + 8192 + bcol * 64 + ((lgrp ^ sB) << 4));
    }
#pragma unroll
    for (int m = 0; m < 2; m++) {
      int arow = wm * 32 + m * 16 + lrow;
      int sw = ((arow & 3) << 1) | ((arow >> 2) & 1);
      f32x4 lo = *(const f32x4*)(cur + arow * 128 + (((lgrp * 2) ^ sw) << 4));
      f32x4 hi = *(const f32x4*)(cur + arow * 128 + (((lgrp * 2 + 1) ^ sw) << 4));
      bfrag am;
      am[0] = (__bf16)lo.x; am[1] = (__bf16)lo.y; am[2] = (__bf16)lo.z; am[3] = (__bf16)lo.w;
      am[4] = (__bf16)hi.x; am[5] = (__bf16)hi.y; am[6] = (__bf16)hi.z; am[7] = (__bf16)hi.w;
#pragma unroll
      for (int n = 0; n < 4; n++)
        acc[m][n] = __builtin_amdgcn_mfma_f32_16x16x32_bf16(am, bf[n], acc[m][n], 0, 0, 0);
    }
    __builtin_amdgcn_s_barrier();
    asm volatile("" ::: "memory");
  }

  // --- write T tile f32 into sf [64][256] (64KB, reuses staging LDS) ---
  float* sf = (float*)sm;
#pragma unroll
  for (int m = 0; m < 2; m++) {
    int row = wm * 32 + m * 16 + lgrp * 4;
#pragma unroll
    for (int n = 0; n < 4; n++) {
      int col = wn * 64 + n * 16 + lrow;
#pragma unroll
      for (int rr = 0; rr < 4; rr++)
        sf[(row + rr) * 256 + col] = acc[m][n][rr];
    }
  }
  __builtin_amdgcn_s_barrier();
  asm volatile("" ::: "memory");

  // --- per-wave epilogue: 8 rows each ---
  const float bb = b_bil[0];
#pragma unroll
  for (int r = 0; r < 8; ++r) {
    const int row = wid * 8 + r;
    const int b = wg * 64 + row;
    const int bp = (b == 0) ? 8190 : (b - 1);
    f32x4 tv = *(const f32x4*)(sf + row * 256 + lane * 4);
    f32x4 cv = *(const f32x4*)(C + (size_t)b * 256 + lane * 4);
    f32x4 cp = *(const f32x4*)(C + (size_t)bp * 256 + lane * 4);
    f32x4 hv = *(const f32x4*)(Hmv + (size_t)b * 256 + lane * 4);
    f32x4 d0 = hv - cv + 1e-6f;
    f32x4 d1 = hv - cp + 1e-6f;
    float s0 = tv.x * cv.x + tv.y * cv.y + tv.z * cv.z + tv.w * cv.w;
    float s1 = tv.x * cp.x + tv.y * cp.y + tv.z * cp.z + tv.w * cp.w;
    float p = d0.x * d0.x + d0.y * d0.y + d0.z * d0.z + d0.w * d0.w;
    float q = d1.x * d1.x + d1.y * d1.y + d1.z * d1.z + d1.w * d1.w;
#pragma unroll
    for (int m = 1; m < 64; m <<= 1) {
      s0 += __shfl_xor(s0, m, 64);
      s1 += __shfl_xor(s1, m, 64);
      p  += __shfl_xor(p, m, 64);
      q  += __shfl_xor(q, m, 64);
    }
    if (lane == 0) {
      out[b] = s0 + bb;
      out[8192 + b] = s1 + bb;
      out[16384 + b] = fmaxf(0.0f, sqrtf(p) - sqrtf(q) + 0.5f);
    }
  }
}

// ---------------- launch -----------------------------------------------------
extern "C" void kernel_launch(void* const* d_in, const int* in_sizes, int n_in,
                              void* d_out, int out_size, void* d_ws, size_t ws_size,
                              hipStream_t stream) {
  (void)in_sizes; (void)n_in; (void)out_size; (void)ws_size;
  const float* seq1 = (const float*)d_in[0];
  const float* adj  = (const float*)d_in[1];
  const float* Wg   = (const float*)d_in[2];
  const float* bg   = (const float*)d_in[3];
  const float* pa   = (const float*)d_in[4];
  const float* Wb   = (const float*)d_in[5];
  const float* bb   = (const float*)d_in[6];
  float* out = (float*)d_out;
  char* ws = (char*)d_ws;

  unsigned short* WgT = (unsigned short*)(ws);                 // 256 KB
  unsigned short* WbT = (unsigned short*)(ws + 262144);        // 128 KB
  float* C   = (float*)(ws + 524288);                          // 8 MB
  float* HMV = (float*)(ws + 524288 + 8388608);                // 8 MB

  hipLaunchKernelGGL(conv_w_k, dim3(512), dim3(256), 0, stream, Wg, Wb, WgT, WbT);
  hipLaunchKernelGGL(fused1_k, dim3(1024), dim3(512), 0, stream,
                     seq1, WgT, adj, bg, pa, C, HMV);
  hipLaunchKernelGGL(fused2_k, dim3(128), dim3(512), 0, stream,
                     HMV, WbT, C, HMV, bb, out);
}